// Round 6
// baseline (54232.593 us; speedup 1.0000x reference)
//
#include <hip/hip_runtime.h>

#define T_STEPS 8192
#define HID 1024
#define G4 4096
#define NTHR 512

typedef unsigned int uint32;

// ---------------------------------------------------------------------------
// Roles (blockIdx&7 -> XCD round-robin is a SPEED heuristic only; correctness
// is guarded by a sticky LLC fallback on every mirror poll):
//   b%8==0 : layer-0 recurrent core (32 blocks). 32 units/block, Whh0 rows
//            lane-major: 192 f32/lane in VGPR + 64 f32/lane in LDS.
//   b%8==1 : layer-1 recurrent core (32 blocks). Same layout with Whh1;
//            consumes z = Wih1*h0 + bias from the FF stage (reg-prefetched,
//            tag-checked, self-correcting via blocking re-poll).
//   b%8 in 2..5 : feed-forward stage, 2-way time split: block f=(xcd-2)*32+sl,
//            phase f&1 handles steps u==phase (mod 2), units (f>>1)*16..+15,
//            weights fully in VGPR (128 f32/lane).
//   b%8 in 6..7 : exit.
// __launch_bounds__(512, 2): 2 waves/EU == 1 block/CU (LDS-forced anyway);
// raises VGPR cap to 256 so wv[48] (192 regs) stays register-resident.
// R4 post-mortem: bare launch_bounds(512) capped VGPRs at 128 -> full spill
// of the weight slice -> 6.2 us/step. This is the fix under test.
// Comm (fp32 tagged in 4 low mantissa bits; slot t&7, tag (t>>3)&15):
//   hA/hB: LLC h0/h1 (atomic agent stores; R0-proven visibility)
//   m0/m1: XCD-local mirrors (plain stores; sc0 polls; sticky LLC fallback;
//          one writer block per 128B line — no cross-XCD dirty-line sharing)
//   zB   : LLC z
// Backpressure (equality scans; scan at step t protects publishes t+1..t+4):
//   L0 wave7 @t%4==0: z reps of steps t-4 AND t-5 (both FF parities, combined
//     into ONE spin loop) => any h0_{s-8} overwritten at step s<=t+4 was fully
//     read (z_u published => that FF block passed its barrier => all its
//     waves done polling h0_u).
//   FF wave0 every 2nd handled step: h1 rep of u-4 => L1 >= u-4 => z slot
//     (u-8) consumed before overwrite.
//   Tag-skip freedom: a scanned slot can only be overwritten by a producer
//   that is itself blocked behind the scanner (audited per loop above).
// Deadlock audit of scan-before-gather ordering: L0@t's scan waits only on
// FF steps t-4/t-5, which need only h0_{<=t-4} (already published; L0
// publishes h0_t BEFORE the scan) and L1 progress >= t-9 (holds by the
// gather induction) -> no wait cycle.
// ---------------------------------------------------------------------------

__device__ inline float sigm(float x){ return 1.0f/(1.0f+__expf(-x)); }
__device__ inline float tanh_f(float x){
    x = fminf(fmaxf(x,-15.f),15.f);
    float e = __expf(-2.0f*x);
    return (1.0f-e)/(1.0f+e);
}
__device__ inline uint32 tagf(float f, uint32 tg){
    union{float f;uint32 u;}a; a.f=f; return (a.u & ~15u)|tg;
}
__device__ inline float u2f(uint32 u){ union{uint32 u;float f;}a; a.u=u; return a.f; }

// publish: relaxed agent atomic store (R0/R1-proven visible to sc0sc1 loads)
__device__ __forceinline__ void pub(uint32* p, uint32 v){
    __hip_atomic_store(p, v, __ATOMIC_RELAXED, __HIP_MEMORY_SCOPE_AGENT);
}
__device__ __forceinline__ void stmir(uint32* p, uint32 v){
    asm volatile("global_store_dword %0, %1, off" :: "v"(p), "v"(v) : "memory");
}
__device__ __forceinline__ uint2 ld2_mir(const uint32* p){
    uint2 v;
    asm volatile("global_load_dwordx2 %0, %1, off sc0\ns_waitcnt vmcnt(0)"
                 : "=v"(v) : "v"(p) : "memory");
    __builtin_amdgcn_sched_barrier(0);
    return v;
}
__device__ __forceinline__ uint2 ld2_llc(const uint32* p){
    uint2 v;
    asm volatile("global_load_dwordx2 %0, %1, off sc0 sc1\ns_waitcnt vmcnt(0)"
                 : "=v"(v) : "v"(p) : "memory");
    __builtin_amdgcn_sched_barrier(0);
    return v;
}
__device__ __forceinline__ uint4 ld4_llc(const uint32* p){
    uint4 v;
    asm volatile("global_load_dwordx4 %0, %1, off sc0 sc1\ns_waitcnt vmcnt(0)"
                 : "=v"(v) : "v"(p) : "memory");
    __builtin_amdgcn_sched_barrier(0);
    return v;
}
__device__ __forceinline__ void issue4(uint4& r, const uint32* p){
    asm volatile("global_load_dwordx4 %0, %1, off sc0 sc1" : "=v"(r) : "v"(p) : "memory");
}
__device__ __forceinline__ uint32 ld1_llc(const uint32* p){
    uint32 v;
    asm volatile("global_load_dword %0, %1, off sc0 sc1\ns_waitcnt vmcnt(0)"
                 : "=v"(v) : "v"(p) : "memory");
    __builtin_amdgcn_sched_barrier(0);
    return v;
}
// two independent dword polls, one waitcnt (combined backpressure scan)
__device__ __forceinline__ void ld1x2_llc(const uint32* p1, const uint32* p2,
                                          uint32& a, uint32& b){
    asm volatile("global_load_dword %0, %2, off sc0 sc1\n\t"
                 "global_load_dword %1, %3, off sc0 sc1\n\t"
                 "s_waitcnt vmcnt(0)"
                 : "=&v"(a), "=&v"(b) : "v"(p1), "v"(p2) : "memory");
    __builtin_amdgcn_sched_barrier(0);
}

// out[m][j*4+gate] = A[m][:].W[gate*H+j][:] + bi + bh   (unit-major layout)
__global__ __launch_bounds__(256)
void gemm_xg(const float* __restrict__ A, const float* __restrict__ W,
             const float* __restrict__ bi, const float* __restrict__ bh,
             float* __restrict__ out)
{
    __shared__ float As[16][65];
    __shared__ float Bs[16][65];
    const int tid = threadIdx.x;
    const int m0 = blockIdx.y * 64, n0 = blockIdx.x * 64;
    const int tm = tid & 15, tn = tid >> 4;
    const int row = tid >> 2, q = tid & 3;
    float acc[4][4] = {{0.f}};
    for (int k0 = 0; k0 < HID; k0 += 16) {
        float4 a = *(const float4*)(A + (size_t)(m0 + row) * HID + k0 + q * 4);
        float4 b = *(const float4*)(W + (size_t)(n0 + row) * HID + k0 + q * 4);
        __syncthreads();
        As[q*4+0][row] = a.x; As[q*4+1][row] = a.y; As[q*4+2][row] = a.z; As[q*4+3][row] = a.w;
        Bs[q*4+0][row] = b.x; Bs[q*4+1][row] = b.y; Bs[q*4+2][row] = b.z; Bs[q*4+3][row] = b.w;
        __syncthreads();
#pragma unroll
        for (int kk = 0; kk < 16; ++kk) {
            float av[4], bv[4];
#pragma unroll
            for (int i = 0; i < 4; ++i) { av[i] = As[kk][tm*4+i]; bv[i] = Bs[kk][tn*4+i]; }
#pragma unroll
            for (int i = 0; i < 4; ++i)
#pragma unroll
                for (int j = 0; j < 4; ++j) acc[i][j] += av[i] * bv[j];
        }
    }
#pragma unroll
    for (int i = 0; i < 4; ++i) {
        int m = m0 + tm * 4 + i;
#pragma unroll
        for (int j = 0; j < 4; ++j) {
            int n = n0 + tn * 4 + j;
            float v = acc[i][j] + bi[n] + bh[n];
            int jd = n & (HID - 1), gate = n >> 10;
            out[(size_t)m * G4 + jd * 4 + gate] = v;
        }
    }
}

__global__ __launch_bounds__(NTHR, 2)
void lstm_fused(const float* __restrict__ Whh0, const float* __restrict__ xg,
                const float* __restrict__ Wih1, const float* __restrict__ Whh1,
                const float* __restrict__ bih1, const float* __restrict__ bhh1,
                float* __restrict__ outF,
                uint32* __restrict__ hA, uint32* __restrict__ hB,
                uint32* __restrict__ zB, uint32* __restrict__ m0,
                uint32* __restrict__ m1)
{
    __shared__ float4 wlds4[16][512];                 // 128 KB LDS weight slice
    __shared__ __align__(16) float hl[2][1024];       // gathered h, dbuf

    const int b = blockIdx.x, tid = threadIdx.x;
    const int xcd = b & 7, sl = b >> 3;
    const int wave = tid >> 6, lane = tid & 63;
    if (xcd >= 6) return;

    if (xcd < 2) {
        // ================= recurrent core (layer = xcd) =================
        const bool isL1 = (xcd == 1);
        const float* W = isL1 ? Whh1 : Whh0;
        uint32* mir = isL1 ? m1 : m0;
        uint32* gho = isL1 ? hB : hA;
        const int q = lane >> 4;                      // quarter 0..3
        const int row = wave * 16 + (lane & 15);      // 0..127
        const int grow = (row & 3) * HID + sl * 32 + (row >> 2);
        const float* wr = W + (size_t)grow * HID;
        // lane-major weights, pre-rotated by q so the 4 q-groups hit
        // disjoint bank quads on every h read (float4 granularity).
        float4 wv[48];
#pragma unroll
        for (int e = 0; e < 48; ++e)
            wv[e] = *(const float4*)(wr + 4 * (q * 64 + ((e + q) & 63)));
#pragma unroll
        for (int k = 0; k < 16; ++k)
            wlds4[k][tid] = *(const float4*)(wr + 4 * (q * 64 + ((48 + k + q) & 63)));
        for (int i = tid; i < HID; i += NTHR) hl[0][i] = 0.f;

        const int xoff = sl * 128 + wave * 16 + (lane & 12);  // gate-input offset
        float4 xv;                 // gate input for current step
        float4 xnx;                // L0: in-flight x (compiler-managed load)
        uint4  znx;                // L1: in-flight z (tag-checked, self-correcting)
        if (!isL1) xnx = *(const float4*)(xg + xoff);         // x_0
        else       issue4(znx, zB + xoff);                    // z_0 (slot 0)
        float c = 0.f;
        bool useLLC = false;
        __syncthreads();

        for (int t = 0; ; ++t) {
            // ---- dot: 256 MACs/lane over this lane's 256-elem slice ----
            const float* hp = hl[t & 1];
            float a0 = 0.f, a1 = 0.f;
#pragma unroll
            for (int e = 0; e < 48; ++e) {
                const float4 h4 = *(const float4*)(hp + 4 * (q * 64 + ((e + q) & 63)));
                a0 += wv[e].x * h4.x + wv[e].y * h4.y;
                a1 += wv[e].z * h4.z + wv[e].w * h4.w;
            }
#pragma unroll
            for (int k = 0; k < 16; ++k) {
                const float4 wk = wlds4[k][tid];
                const float4 h4 = *(const float4*)(hp + 4 * (q * 64 + ((48 + k + q) & 63)));
                a0 += wk.x * h4.x + wk.y * h4.y;
                a1 += wk.z * h4.z + wk.w * h4.w;
            }
            float s = a0 + a1;
            s += __shfl_xor(s, 16, 64);               // combine 4 quarters
            s += __shfl_xor(s, 32, 64);
            const int base = lane & 60;               // this lane's unit base
            float si = __shfl(s, base + 0, 64);
            float sf = __shfl(s, base + 1, 64);
            float sg = __shfl(s, base + 2, 64);
            float so = __shfl(s, base + 3, 64);
            // ---- adopt gate input for step t (in flight since last step) ----
            if (isL1) {
                asm volatile("s_waitcnt vmcnt(0)" ::: "memory");
                __builtin_amdgcn_sched_barrier(0);
                const uint32 ztg = (uint32)((t >> 3) & 15);
                if (!__all(((znx.x & 15u) == ztg) & ((znx.y & 15u) == ztg) &
                           ((znx.z & 15u) == ztg) & ((znx.w & 15u) == ztg))) {
                    const uint32* p = zB + (size_t)(t & 7) * G4 + xoff;
                    for (;;) {
                        znx = ld4_llc(p);
                        if (__all(((znx.x & 15u) == ztg) & ((znx.y & 15u) == ztg) &
                                  ((znx.z & 15u) == ztg) & ((znx.w & 15u) == ztg))) break;
                    }
                }
                xv.x = u2f(znx.x); xv.y = u2f(znx.y); xv.z = u2f(znx.z); xv.w = u2f(znx.w);
            } else {
                xv = xnx;
            }
            float ig = sigm(xv.x + si);
            float fg = sigm(xv.y + sf);
            float gg = tanh_f(xv.z + sg);
            float og = sigm(xv.w + so);
            c = fg * c + ig * gg;
            float h = og * tanh_f(c);

            const int slot = t & 7;
            const uint32 tg = (uint32)((t >> 3) & 15);
            if (isL1 && t == T_STEPS - 1) {
                if ((lane & 3) == 0 && q == 0)
                    outF[sl * 32 + wave * 4 + (lane >> 2)] = h;
                break;
            }
            if ((lane & 3) == 0 && q == 0) {
                const int j = sl * 32 + wave * 4 + (lane >> 2);
                const uint32 tv = tagf(h, tg);
                stmir(mir + slot * HID + j, tv);      // XCD-local fast path
                pub(gho + slot * HID + j, tv);        // LLC (FF + fallback)
            }
            if (t == T_STEPS - 1) break;
            // ---- backpressure first (wave7 only): combined both-parity spin;
            //      overlaps with other blocks' h publishes before our gather ----
            if (!isL1 && wave == 7 && (t & 3) == 0 && t >= 4) {
                const uint32 stgA = (uint32)(((t - 4) >> 3) & 15);
                const uint32* pA = zB + (size_t)((t - 4) & 7) * G4 + lane * 64;
                if (t >= 8) {
                    const uint32 stgB = (uint32)(((t - 5) >> 3) & 15);
                    const uint32* pB = zB + (size_t)((t - 5) & 7) * G4 + lane * 64;
                    for (;;) {
                        uint32 va, vb;
                        ld1x2_llc(pA, pB, va, vb);
                        if (__all(((va & 15u) == stgA) & ((vb & 15u) == stgB))) break;
                    }
                } else {
                    for (;;) { if (__all((ld1_llc(pA) & 15u) == stgA)) break; }
                }
            }
            // ---- gather h_t -> hl[(t+1)&1]; wave polls its 128-dword seg ----
            {
                float* dst = hl[(t + 1) & 1] + wave * 128 + lane * 2;
                const uint32* pm = mir + slot * HID + wave * 128 + lane * 2;
                const uint32* pl = gho + slot * HID + wave * 128 + lane * 2;
                int it = 0; const int cap = (t == 0) ? 4096 : 256;
                for (;;) {
                    uint2 v = useLLC ? ld2_llc(pl) : ld2_mir(pm);
                    if (__all(((v.x & 15u) == tg) & ((v.y & 15u) == tg))) {
                        dst[0] = u2f(v.x); dst[1] = u2f(v.y); break;
                    }
                    if (!useLLC && ++it >= cap) useLLC = true;  // sticky fallback
                }
            }
            // ---- prefetch next gate input (flies across barrier+dots) ----
            if (isL1) {
                if (t + 1 < T_STEPS)
                    issue4(znx, zB + (size_t)((t + 1) & 7) * G4 + xoff);
            } else if (t + 1 < T_STEPS) {
                xnx = *(const float4*)(xg + (size_t)(t + 1) * G4 + xoff);
            }
            __syncthreads();
        }
    } else {
        // ================= feed-forward: z = Wih1*h0 + bias =================
        const int f = (xcd - 2) * 32 + sl;            // 0..127
        const int ph = f & 1, kp = f >> 1;            // phase, unit base kp*16
        const int q8 = lane >> 3;
        const int row = wave * 8 + (lane & 7);        // 0..63
        const int grow = (row & 3) * HID + kp * 16 + (row >> 2);
        const float* wr = Wih1 + (size_t)grow * HID;
        float4 wf[32];
#pragma unroll
        for (int e = 0; e < 32; ++e)
            wf[e] = *(const float4*)(wr + 4 * (q8 * 32 + ((e + q8) & 31)));
        const float bia = bih1[grow] + bhh1[grow];
        __syncthreads();

        for (int u = ph; u < T_STEPS; u += 2) {
            const int slot = u & 7;
            const uint32 tg = (uint32)((u >> 3) & 15);
            // poll full h0_u (LLC): all waves, 2 dwords/lane
            {
                const uint32* p = hA + slot * HID + tid * 2;
                uint2 v;
                for (;;) {
                    v = ld2_llc(p);
                    if (__all(((v.x & 15u) == tg) & ((v.y & 15u) == tg))) break;
                }
                float* hb = hl[(u >> 1) & 1];
                hb[tid * 2] = u2f(v.x); hb[tid * 2 + 1] = u2f(v.y);
            }
            // backpressure vs L1 (before this step's z store — ordering matters)
            if (wave == 0 && ((u >> 1) & 1) == 0 && u >= 4) {
                const uint32 stg = (uint32)(((u - 4) >> 3) & 15);
                const uint32* p = hB + (size_t)((u - 4) & 7) * HID + (lane & 31) * 32;
                for (;;) { if (__all((ld1_llc(p) & 15u) == stg)) break; }
            }
            __syncthreads();
            const float* hp = hl[(u >> 1) & 1];
            float a0 = 0.f, a1 = 0.f;
#pragma unroll
            for (int e = 0; e < 32; ++e) {
                const float4 h4 = *(const float4*)(hp + 4 * (q8 * 32 + ((e + q8) & 31)));
                a0 += wf[e].x * h4.x + wf[e].y * h4.y;
                a1 += wf[e].z * h4.z + wf[e].w * h4.w;
            }
            float s = a0 + a1;
            s += __shfl_xor(s, 8, 64);
            s += __shfl_xor(s, 16, 64);
            s += __shfl_xor(s, 32, 64);
            if (lane < 8) {
                const int zi = (kp * 16 + wave * 2 + (lane >> 2)) * 4 + (lane & 3);
                pub(zB + (size_t)slot * G4 + zi, tagf(s + bia, tg));
            }
        }
    }
}

extern "C" void kernel_launch(void* const* d_in, const int* in_sizes, int n_in,
                              void* d_out, int out_size, void* d_ws, size_t ws_size,
                              hipStream_t stream)
{
    const float* x    = (const float*)d_in[0];
    const float* Wih0 = (const float*)d_in[1];
    const float* Whh0 = (const float*)d_in[2];
    const float* bih0 = (const float*)d_in[3];
    const float* bhh0 = (const float*)d_in[4];
    const float* Wih1 = (const float*)d_in[5];
    const float* Whh1 = (const float*)d_in[6];
    const float* bih1 = (const float*)d_in[7];
    const float* bhh1 = (const float*)d_in[8];

    char* ws = (char*)d_ws;
    float* xg = (float*)ws;                          // 134217728 B
    size_t off = 134217728ull;
    uint32* hA = (uint32*)(ws + off); off += 32768;  // 8*1024*4
    uint32* hB = (uint32*)(ws + off); off += 32768;
    uint32* m0 = (uint32*)(ws + off); off += 32768;
    uint32* m1 = (uint32*)(ws + off); off += 32768;
    uint32* zB = (uint32*)(ws + off); off += 131072; // 8*4096*4

    // 0xFF fill -> tag 15 everywhere; slot s first expects tag 0.
    (void)hipMemsetAsync(ws + 134217728ull, 0xFF, 262144, stream);

    dim3 gg(G4 / 64, T_STEPS / 64);
    gemm_xg<<<gg, 256, 0, stream>>>(x, Wih0, bih0, bhh0, xg);
    lstm_fused<<<256, NTHR, 0, stream>>>(Whh0, xg, Wih1, Whh1, bih1, bhh1,
                                         (float*)d_out, hA, hB, zB, m0, m1);
}

// Round 9
// 35919.867 us; speedup vs baseline: 1.5098x; 1.5098x over previous
//
#include <hip/hip_runtime.h>

#define T_STEPS 8192
#define HID 1024
#define G4 4096
#define NTHR 512
#define NSLOT 8

typedef unsigned int uint32;

// ---------------------------------------------------------------------------
// Roles (blockIdx&7 -> XCD round-robin is a SPEED heuristic only; correctness
// is guarded by a sticky LLC fallback on every mirror poll):
//   b%8==0 : layer-0 recurrent core (32 blocks). 32 units/block.
//   b%8==1 : layer-1 recurrent core (32 blocks); consumes z = Wih1*h0 + bias
//            from FF (reg-prefetched, tag-checked, blocking re-poll).
//   b%8 in 2..5 : FF stage, 2-way time split (128 blocks).
//   b%8 in 6..7 : exit.
// Core dot layout: lane=(p,s), p=wave*8+(lane>>3) row-pair, s=lane&7 k-slice
// of 128. Rows 2p,2p+1 share one h-slice: 32 h-float4 reads/lane, weights
// 48 f4 VGPR + 16 f4 LDS. h stored chunk-strided (132 floats) so a wave's
// h read = 8 distinct addrs on 8 distinct bank quads (broadcast).
// amdgpu_waves_per_eu(2,2): VGPR cap 256 (launch_bounds(,2) gave 128 - R6).
// Comm: EXACT R4/R6 hardware-proven memory map (262144 B beyond xg; ws_size
// was never validated, so the R7 1 MB extension is reverted as a fault risk).
// fp32 tagged, 4 low mantissa bits = (t>>3)&15, slot t&7, depth 8:
//   hA/hB LLC h0/h1; m0/m1 XCD-local mirrors (plain store, sc0 poll, sticky
//   LLC fallback); zB LLC z.
// Backpressure, overtake-proof form (accept tag != prevTag => progress >= v;
// address holds prevTag (not yet) or tag(v)+k (done); wrap needs 128 steps,
// bounded far below by the scans themselves):
//   L0 wave7 @t%4==0,t>=4: z reps of v1=t-4 and (t>=8) v2=t-5 (both FF
//     parities) => publishes t+1..t+4 overwrite only consumed h0 slots
//     (slot of h0_{s-8}, s-8 in t-7..t-4, covered by parity as in R4 audit).
//   FF wave0 every 2 handled steps, uu>=4: h1 rep of uu-4 => owning L1 >=
//     uu-4 => z slot reuse (distance 8) safe.
//   Value-polls (gather/z-adopt) keep exact-tag equality; slot reuse distance
//   8 steps => adjacent tags differ; producers bounded by scans => no skip.
// Deadlock audit: every spin waits on strictly-earlier pipeline progress
// (L0 publishes h0_t BEFORE its scan; FF scan needs only its own L1 block;
// L1 z-wait needs FF which needs earlier h0/h1) -> wait graph is a DAG.
// ---------------------------------------------------------------------------

__device__ inline float sigm(float x){ return 1.0f/(1.0f+__expf(-x)); }
__device__ inline float tanh_f(float x){
    x = fminf(fmaxf(x,-15.f),15.f);
    float e = __expf(-2.0f*x);
    return (1.0f-e)/(1.0f+e);
}
__device__ inline uint32 tagf(float f, uint32 tg){
    union{float f;uint32 u;}a; a.f=f; return (a.u & ~15u)|tg;
}
__device__ inline float u2f(uint32 u){ union{uint32 u;float f;}a; a.u=u; return a.f; }

__device__ __forceinline__ void pub(uint32* p, uint32 v){
    __hip_atomic_store(p, v, __ATOMIC_RELAXED, __HIP_MEMORY_SCOPE_AGENT);
}
__device__ __forceinline__ void stmir(uint32* p, uint32 v){
    asm volatile("global_store_dword %0, %1, off" :: "v"(p), "v"(v) : "memory");
}
__device__ __forceinline__ uint2 ld2_mir(const uint32* p){
    uint2 v;
    asm volatile("global_load_dwordx2 %0, %1, off sc0\ns_waitcnt vmcnt(0)"
                 : "=v"(v) : "v"(p) : "memory");
    __builtin_amdgcn_sched_barrier(0);
    return v;
}
__device__ __forceinline__ uint2 ld2_llc(const uint32* p){
    uint2 v;
    asm volatile("global_load_dwordx2 %0, %1, off sc0 sc1\ns_waitcnt vmcnt(0)"
                 : "=v"(v) : "v"(p) : "memory");
    __builtin_amdgcn_sched_barrier(0);
    return v;
}
__device__ __forceinline__ uint4 ld4_llc(const uint32* p){
    uint4 v;
    asm volatile("global_load_dwordx4 %0, %1, off sc0 sc1\ns_waitcnt vmcnt(0)"
                 : "=v"(v) : "v"(p) : "memory");
    __builtin_amdgcn_sched_barrier(0);
    return v;
}
__device__ __forceinline__ void issue4(uint4& r, const uint32* p){
    asm volatile("global_load_dwordx4 %0, %1, off sc0 sc1" : "=v"(r) : "v"(p) : "memory");
}
__device__ __forceinline__ uint32 ld1_llc(const uint32* p){
    uint32 v;
    asm volatile("global_load_dword %0, %1, off sc0 sc1\ns_waitcnt vmcnt(0)"
                 : "=v"(v) : "v"(p) : "memory");
    __builtin_amdgcn_sched_barrier(0);
    return v;
}
__device__ __forceinline__ void ld1x2_llc(const uint32* p1, const uint32* p2,
                                          uint32& a, uint32& b){
    asm volatile("global_load_dword %0, %2, off sc0 sc1\n\t"
                 "global_load_dword %1, %3, off sc0 sc1\n\t"
                 "s_waitcnt vmcnt(0)"
                 : "=&v"(a), "=&v"(b) : "v"(p1), "v"(p2) : "memory");
    __builtin_amdgcn_sched_barrier(0);
}

// out[m][j*4+gate] = A[m][:].W[gate*H+j][:] + bi + bh   (unit-major layout)
__global__ __launch_bounds__(256)
void gemm_xg(const float* __restrict__ A, const float* __restrict__ W,
             const float* __restrict__ bi, const float* __restrict__ bh,
             float* __restrict__ out)
{
    __shared__ float As[16][65];
    __shared__ float Bs[16][65];
    const int tid = threadIdx.x;
    const int m0 = blockIdx.y * 64, n0 = blockIdx.x * 64;
    const int tm = tid & 15, tn = tid >> 4;
    const int row = tid >> 2, q = tid & 3;
    float acc[4][4] = {{0.f}};
    for (int k0 = 0; k0 < HID; k0 += 16) {
        float4 a = *(const float4*)(A + (size_t)(m0 + row) * HID + k0 + q * 4);
        float4 b = *(const float4*)(W + (size_t)(n0 + row) * HID + k0 + q * 4);
        __syncthreads();
        As[q*4+0][row] = a.x; As[q*4+1][row] = a.y; As[q*4+2][row] = a.z; As[q*4+3][row] = a.w;
        Bs[q*4+0][row] = b.x; Bs[q*4+1][row] = b.y; Bs[q*4+2][row] = b.z; Bs[q*4+3][row] = b.w;
        __syncthreads();
#pragma unroll
        for (int kk = 0; kk < 16; ++kk) {
            float av[4], bv[4];
#pragma unroll
            for (int i = 0; i < 4; ++i) { av[i] = As[kk][tm*4+i]; bv[i] = Bs[kk][tn*4+i]; }
#pragma unroll
            for (int i = 0; i < 4; ++i)
#pragma unroll
                for (int j = 0; j < 4; ++j) acc[i][j] += av[i] * bv[j];
        }
    }
#pragma unroll
    for (int i = 0; i < 4; ++i) {
        int m = m0 + tm * 4 + i;
#pragma unroll
        for (int j = 0; j < 4; ++j) {
            int n = n0 + tn * 4 + j;
            float v = acc[i][j] + bi[n] + bh[n];
            int jd = n & (HID - 1), gate = n >> 10;
            out[(size_t)m * G4 + jd * 4 + gate] = v;
        }
    }
}

__global__ void
__attribute__((amdgpu_flat_work_group_size(NTHR, NTHR), amdgpu_waves_per_eu(2, 2)))
lstm_fused(const float* __restrict__ Whh0, const float* __restrict__ xg,
           const float* __restrict__ Wih1, const float* __restrict__ Whh1,
           const float* __restrict__ bih1, const float* __restrict__ bhh1,
           float* __restrict__ outF,
           uint32* __restrict__ hA, uint32* __restrict__ hB,
           uint32* __restrict__ zB, uint32* __restrict__ m0,
           uint32* __restrict__ m1)
{
    __shared__ float4 wlds4[16][512];                 // 128 KB LDS weight slice
    __shared__ __align__(16) float hl[2][1056];       // h dbuf, 132-chunked

    const int b = blockIdx.x, tid = threadIdx.x;
    const int xcd = b & 7, sl = b >> 3;
    const int wave = tid >> 6, lane = tid & 63;
    if (xcd >= 6) return;

    if (xcd < 2) {
        // ================= recurrent core (layer = xcd) =================
        const bool isL1 = (xcd == 1);
        const float* W = isL1 ? Whh1 : Whh0;
        uint32* mir = isL1 ? m1 : m0;
        uint32* gho = isL1 ? hB : hA;
        const int s8 = lane & 7;                   // k-slice (128 cols)
        const int p  = wave * 8 + (lane >> 3);     // row-pair 0..63
        const int r0 = 2 * p, r1 = 2 * p + 1;
        const int g0row = (r0 & 3) * HID + sl * 32 + (r0 >> 2);
        const int g1row = (r1 & 3) * HID + sl * 32 + (r1 >> 2);
        const float4* w0p = (const float4*)(W + (size_t)g0row * HID + s8 * 128);
        const float4* w1p = (const float4*)(W + (size_t)g1row * HID + s8 * 128);
        float4 wv0[32], wv1[16];
#pragma unroll
        for (int i = 0; i < 32; ++i) wv0[i] = w0p[i];
#pragma unroll
        for (int i = 0; i < 16; ++i) wv1[i] = w1p[i];
#pragma unroll
        for (int i = 0; i < 16; ++i) wlds4[i][tid] = w1p[16 + i];
        for (int i = tid; i < 2 * 1056; i += NTHR) ((float*)hl)[i] = 0.f;

        const bool act = ((lane & 15) == 0);       // 4 activation lanes/wave
        const int uu_ = wave * 4 + (lane >> 4);    // unit (when act)
        const int jj = sl * 32 + uu_;
        float4 xv, xnx; uint4 znx;
        if (act) {
            if (!isL1) xnx = *(const float4*)(xg + jj * 4);
            else       issue4(znx, zB + jj * 4);   // z_0, slot 0, tag 0
        }
        float c = 0.f, hout = 0.f;
        bool useLLC = false;
        __syncthreads();

        for (int t = 0; ; ++t) {
            // ---- dot: 2 rows x 128 cols per lane; h4 read once, used twice ----
            const float4* h4p = (const float4*)(hl[t & 1] + s8 * 132);
            float acc0 = 0.f, acc1 = 0.f;
#pragma unroll
            for (int i = 0; i < 16; ++i) {
                const float4 h4 = h4p[i];
                acc0 += wv0[i].x*h4.x + wv0[i].y*h4.y + wv0[i].z*h4.z + wv0[i].w*h4.w;
                acc1 += wv1[i].x*h4.x + wv1[i].y*h4.y + wv1[i].z*h4.z + wv1[i].w*h4.w;
            }
#pragma unroll
            for (int i = 16; i < 32; ++i) {
                const float4 h4 = h4p[i];
                const float4 wk = wlds4[i - 16][tid];
                acc0 += wv0[i].x*h4.x + wv0[i].y*h4.y + wv0[i].z*h4.z + wv0[i].w*h4.w;
                acc1 += wk.x*h4.x + wk.y*h4.y + wk.z*h4.z + wk.w*h4.w;
            }
            // reduce over 8 k-slices (lane bits 0-2)
            acc0 += __shfl_xor(acc0, 1, 64); acc1 += __shfl_xor(acc1, 1, 64);
            acc0 += __shfl_xor(acc0, 2, 64); acc1 += __shfl_xor(acc1, 2, 64);
            acc0 += __shfl_xor(acc0, 4, 64); acc1 += __shfl_xor(acc1, 4, 64);
            // even-p lane has (g0,g1); pull (g2,g3) from lane+8 (odd p)
            const float g2 = __shfl_xor(acc0, 8, 64);
            const float g3 = __shfl_xor(acc1, 8, 64);

            const int slot = t & (NSLOT - 1);
            const uint32 tg = (uint32)((t >> 3) & 15);
            if (act) {
                if (isL1) {   // adopt z_t (in flight since last step)
                    asm volatile("s_waitcnt vmcnt(0)" ::: "memory");
                    __builtin_amdgcn_sched_barrier(0);
                    if (!__all(((znx.x & 15u) == tg) & ((znx.y & 15u) == tg) &
                               ((znx.z & 15u) == tg) & ((znx.w & 15u) == tg))) {
                        const uint32* zp = zB + (size_t)slot * G4 + jj * 4;
                        for (;;) {
                            znx = ld4_llc(zp);
                            if (__all(((znx.x & 15u) == tg) & ((znx.y & 15u) == tg) &
                                      ((znx.z & 15u) == tg) & ((znx.w & 15u) == tg))) break;
                        }
                    }
                    xv.x = u2f(znx.x); xv.y = u2f(znx.y);
                    xv.z = u2f(znx.z); xv.w = u2f(znx.w);
                } else {
                    xv = xnx;
                }
                float ig = sigm(xv.x + acc0);
                float fg = sigm(xv.y + acc1);
                float gg = tanh_f(xv.z + g2);
                float og = sigm(xv.w + g3);
                c = fg * c + ig * gg;
                hout = og * tanh_f(c);
            }
            if (isL1 && t == T_STEPS - 1) {
                if (act) outF[jj] = hout;
                break;
            }
            if (act) {
                const uint32 tv = tagf(hout, tg);
                stmir(mir + slot * HID + jj, tv);     // XCD-local fast path
                pub(gho + slot * HID + jj, tv);       // LLC (FF + fallback)
            }
            if (t == T_STEPS - 1) break;
            // ---- backpressure (L0 wave7, every 4 steps, overtake-proof) ----
            if (!isL1 && wave == 7 && (t & 3) == 0 && t >= 4) {
                const int v1 = t - 4;
                const uint32 pv1 = (uint32)(((v1 >> 3) - 1) & 15);
                const uint32* pA = zB + (size_t)(v1 & (NSLOT - 1)) * G4 + lane * 64;
                if (t >= 8) {
                    const int v2 = t - 5;
                    const uint32 pv2 = (uint32)(((v2 >> 3) - 1) & 15);
                    const uint32* pB = zB + (size_t)(v2 & (NSLOT - 1)) * G4 + lane * 64;
                    for (;;) {
                        uint32 va, vb;
                        ld1x2_llc(pA, pB, va, vb);
                        if (__all(((va & 15u) != pv1) & ((vb & 15u) != pv2))) break;
                    }
                } else {
                    for (;;) { if (__all((ld1_llc(pA) & 15u) != pv1)) break; }
                }
            }
            // ---- gather h_t -> other parity buffer (chunk wave, 2 dw/lane) ----
            {
                float* dst = hl[(t + 1) & 1] + wave * 132 + lane * 2;
                const uint32* pm = mir + slot * HID + wave * 128 + lane * 2;
                const uint32* pl = gho + slot * HID + wave * 128 + lane * 2;
                int it = 0; const int cap = (t == 0) ? 4096 : 256;
                for (;;) {
                    uint2 v = useLLC ? ld2_llc(pl) : ld2_mir(pm);
                    if (__all(((v.x & 15u) == tg) & ((v.y & 15u) == tg))) {
                        float2 w2; w2.x = u2f(v.x); w2.y = u2f(v.y);
                        *(float2*)dst = w2; break;
                    }
                    if (!useLLC && ++it >= cap) useLLC = true;  // sticky fallback
                }
            }
            // ---- prefetch next gate input ----
            if (act && t + 1 < T_STEPS) {
                if (isL1) issue4(znx, zB + (size_t)((t + 1) & (NSLOT - 1)) * G4 + jj * 4);
                else      xnx = *(const float4*)(xg + (size_t)(t + 1) * G4 + jj * 4);
            }
            __syncthreads();
        }
    } else {
        // ================= feed-forward: z = Wih1*h0 + bias =================
        const int f = (xcd - 2) * 32 + sl;            // 0..127
        const int ph = f & 1, kp = f >> 1;            // phase, unit base kp*16
        const int q8 = lane >> 3;
        const int rowf = wave * 8 + (lane & 7);       // 0..63
        const int growf = (rowf & 3) * HID + kp * 16 + (rowf >> 2);
        const float* wr = Wih1 + (size_t)growf * HID;
        float4 wf[32];
#pragma unroll
        for (int e = 0; e < 32; ++e)
            wf[e] = *(const float4*)(wr + 4 * (q8 * 32 + ((e + q8) & 31)));
        const float bia = bih1[growf] + bhh1[growf];
        __syncthreads();

        for (int uu = ph; uu < T_STEPS; uu += 2) {
            const int slot = uu & (NSLOT - 1);
            const uint32 tg = (uint32)((uu >> 3) & 15);
            // poll full h0_uu (LLC): all waves, 2 dwords/lane, linear layout
            {
                const uint32* pp = hA + (size_t)slot * HID + tid * 2;
                uint2 v;
                for (;;) {
                    v = ld2_llc(pp);
                    if (__all(((v.x & 15u) == tg) & ((v.y & 15u) == tg))) break;
                }
                float* hb = hl[(uu >> 1) & 1];
                hb[tid * 2] = u2f(v.x); hb[tid * 2 + 1] = u2f(v.y);
            }
            // backpressure vs L1 (overtake-proof), before this step's z store
            if (wave == 0 && ((uu >> 1) & 1) == 0 && uu >= 4) {
                const int v1 = uu - 4;
                const uint32 pv1 = (uint32)(((v1 >> 3) - 1) & 15);
                const uint32* pp = hB + (size_t)(v1 & (NSLOT - 1)) * HID + (lane & 31) * 32;
                for (;;) { if (__all((ld1_llc(pp) & 15u) != pv1)) break; }
            }
            __syncthreads();
            const float* hp = hl[(uu >> 1) & 1];
            float a0 = 0.f, a1 = 0.f;
#pragma unroll
            for (int e = 0; e < 32; ++e) {
                const float4 h4 = *(const float4*)(hp + 4 * (q8 * 32 + ((e + q8) & 31)));
                a0 += wf[e].x * h4.x + wf[e].y * h4.y;
                a1 += wf[e].z * h4.z + wf[e].w * h4.w;
            }
            float s = a0 + a1;
            s += __shfl_xor(s, 8, 64);
            s += __shfl_xor(s, 16, 64);
            s += __shfl_xor(s, 32, 64);
            if (lane < 8) {
                const int zi = (kp * 16 + wave * 2 + (lane >> 2)) * 4 + (lane & 3);
                pub(zB + (size_t)slot * G4 + zi, tagf(s + bia, tg));
            }
        }
    }
}

extern "C" void kernel_launch(void* const* d_in, const int* in_sizes, int n_in,
                              void* d_out, int out_size, void* d_ws, size_t ws_size,
                              hipStream_t stream)
{
    const float* x    = (const float*)d_in[0];
    const float* Wih0 = (const float*)d_in[1];
    const float* Whh0 = (const float*)d_in[2];
    const float* bih0 = (const float*)d_in[3];
    const float* bhh0 = (const float*)d_in[4];
    const float* Wih1 = (const float*)d_in[5];
    const float* Whh1 = (const float*)d_in[6];
    const float* bih1 = (const float*)d_in[7];
    const float* bhh1 = (const float*)d_in[8];

    char* ws = (char*)d_ws;
    float* xg = (float*)ws;                          // 134217728 B
    size_t off = 134217728ull;
    uint32* hA = (uint32*)(ws + off); off += 32768;  // 8*1024*4
    uint32* hB = (uint32*)(ws + off); off += 32768;
    uint32* m0 = (uint32*)(ws + off); off += 32768;
    uint32* m1 = (uint32*)(ws + off); off += 32768;
    uint32* zB = (uint32*)(ws + off); off += 131072; // 8*4096*4

    // 0xFF fill -> tag 15 everywhere == prevTag of the step-0 family; first
    // exact-tag expectation is tag 0. Same 262144-byte map as R4/R6 (proven).
    (void)hipMemsetAsync(ws + 134217728ull, 0xFF, 262144, stream);

    dim3 gg(G4 / 64, T_STEPS / 64);
    gemm_xg<<<gg, 256, 0, stream>>>(x, Wih0, bih0, bhh0, xg);
    lstm_fused<<<256, NTHR, 0, stream>>>(Whh0, xg, Wih1, Whh1, bih1, bhh1,
                                         (float*)d_out, hA, hB, zB, m0, m1);
}